// Round 5
// baseline (619.957 us; speedup 1.0000x reference)
//
#include <hip/hip_runtime.h>

// LSTM enc(20, in=2) + dec(30, in=h) fused, HID=64, f32 I/O.
// Gates-transposed MFMA recurrence, v_mfma_f32_16x16x32_f16 (K=32).
//   D[n][m] = sum_k W[n][k] h[m][k]; C/D: col=l&15, row=4*(l>>4)+r (m89,
//   dtype-independent).
// k-relabeling: BOTH operands packed with f(q,tg,e) = 32q + 8tg + e
// (a bijection over [0,64); any f applied to A and B identically leaves
// D unchanged). So A-frag q = 8 CONTIGUOUS floats W[n][32q+8tg .. +7],
// and B-frag q = h[32q+8tg .. +7] = one b128 from identity-layout LDS.
// Wave w owns hidden j in [16w,16w+16). Cross-wave h exchange through a
// double-buffered XOR-swizzled LDS tile, 1 barrier/step:
//   write: wave w lane(m,tg) stores jb=4w+tg at slot jb^(m&14) (free)
//   read:  b128 at slot (8q+2tg)^(m&14) -> h[32q+8tg..+7] (free)
// Output path: Linear(h) via deferred MFMA (wave0=tile0, wave1=tile1) on the
// b-frags read at iteration end; LA-frag same f-pack (single f16, NOT scaled).
// TWO batch tiles per block (32 batch) share weight VGPRs and the barrier.
//
// R6: scale-folded gates (exp2 domain) + single-rcp fused cell math:
//   7 trans/h (5 exp2 + 2 rcp).  886->830 rocprof; VALU 64->59.
// R7: pk-f32 vectorized cell math + unroll 2.  VALU 59->55.7; combined
//   VALU+MFMA = 94.6% -> issue-saturated; only lever is fewer cycles.
// R8: bf16 -> f16 precision scheme (f16-RNE h, no h-lo): 48 -> 32
//   MFMAs/step.  rocprof 850->655, wall 709->570; absmax UNCHANGED 2.4e-4.
// R9: single f16-RNE W (drop W-lo): 32 -> 16 MFMAs/step.  rocprof 655->548,
//   wall 570->468, MfmaUtil 18.1 (predicted 18), absmax STILL 2.4e-4.
// R10 (this round): occupancy 2 -> 4 blocks/CU.  Cycle inventory at R9:
//   per wave-step 1644 SIMD-cy = 296 MFMA (18%) + 1019 VALU (62%, of which
//   ~896 = 56 trans x 16cy quarter-rate) + ~330 idle (dep stalls at only
//   2 waves/SIMD).  Trans count is at the algebraic floor; the lever is
//   filling the idle with resident waves.  VGPR now 108 <= 128 budget ->
//   __launch_bounds__(256, 4) (was 2, a bf16-era holdover).  Barriers
//   decouple the 4 blocks so trans overlaps MFMA/LDS across blocks.
//   Floor: VALU-issue 1019/1644 = 62% of current wall.

#define LOG2E 1.44269504088896340736f
#define TWO_LOG2E 2.88539008177792681472f

typedef __attribute__((ext_vector_type(4))) short short4v;
typedef __attribute__((ext_vector_type(4))) float float4v;
typedef _Float16 __attribute__((ext_vector_type(8))) half8v;

#if defined(__HIP_DEVICE_COMPILE__)
#define MFMAH(a, b, c) __builtin_amdgcn_mfma_f32_16x16x32_f16((a), (b), (c), 0, 0, 0)
#else
#define MFMAH(a, b, c) (c)
#endif

__device__ __forceinline__ float4v exp2v4(float4v x) {
  float4v r;
  r[0] = __builtin_amdgcn_exp2f(x[0]);
  r[1] = __builtin_amdgcn_exp2f(x[1]);
  r[2] = __builtin_amdgcn_exp2f(x[2]);
  r[3] = __builtin_amdgcn_exp2f(x[3]);
  return r;
}
__device__ __forceinline__ float4v rcpv4(float4v x) {
  float4v r;
  r[0] = __builtin_amdgcn_rcpf(x[0]);
  r[1] = __builtin_amdgcn_rcpf(x[1]);
  r[2] = __builtin_amdgcn_rcpf(x[2]);
  r[3] = __builtin_amdgcn_rcpf(x[3]);
  return r;
}

// Fused LSTM cell update on 4 rows (pk-f32).  a[0..3] = gates i,f,g,o
// PRE-SCALED (i,f,o by -log2e; g by 2log2e).  c holds 2log2e*cell.
// Emits h as 4 f16 (RNE) bit-patterns.
__device__ __forceinline__ void cellact(const float4v* a, float4v& c,
                                        short4v& hh) {
  const float4v one = {1.f, 1.f, 1.f, 1.f};
  const float4v clo = {-36.f, -36.f, -36.f, -36.f};
  const float4v chi = {36.f, 36.f, 36.f, 36.f};
  float4v Ei = exp2v4(a[0]);                    // e^{-i}
  float4v Ef = exp2v4(a[1]);                    // e^{-f}
  float4v Eg = exp2v4(a[2]);                    // e^{2g}
  float4v Eo = exp2v4(a[3]);                    // e^{-o}
  float4v t1 = one + Ei;
  float4v t2 = one + Eg;
  float4v t3 = one + Ef;
  float4v t4s = Eg * TWO_LOG2E - TWO_LOG2E;     // 2log2e*(Eg-1), pk_fma
  float4v P = t1 * t2;
  float4v num = c * P + t4s * t3;               // pk_mul + pk_fma
  float4v cs = num * rcpv4(P * t3);             // 2log2e * c_new
  c = cs;
  float4v cl = __builtin_elementwise_min(__builtin_elementwise_max(cs, clo), chi);
  float4v Ec = exp2v4(cl);                      // e^{2*c_new}
  float4v h = (Ec - one) * rcpv4((one + Ec) * (one + Eo));
#pragma unroll
  for (int r = 0; r < 4; ++r) {
    _Float16 hf = (_Float16)h[r];               // v_cvt_f16_f32 (RNE)
    hh[r] = (short)__builtin_bit_cast(unsigned short, hf);
  }
}

__global__ __launch_bounds__(256, 4) void lstm_fused(
    const float* __restrict__ x,     // [B][20][2]
    const float* __restrict__ eWih,  // [256][2]
    const float* __restrict__ eWhh,  // [256][64]
    const float* __restrict__ ebih,  // [256]
    const float* __restrict__ ebhh,  // [256]
    const float* __restrict__ dWih,  // [256][64]
    const float* __restrict__ dWhh,  // [256][64]
    const float* __restrict__ dbih,  // [256]
    const float* __restrict__ dbhh,  // [256]
    const float* __restrict__ linW,  // [2][64]
    const float* __restrict__ linb,  // [2]
    float* __restrict__ out,         // [B][30][2]
    int B) {
  const int tid = threadIdx.x;
  const int w   = tid >> 6;    // wave: hidden block [16w, 16w+16)
  const int l   = tid & 63;
  const int m   = l & 15;      // batch col within tile
  const int tg  = l >> 4;
  const int msk = m & 14;
  const int wslot = (((w << 2) | tg) ^ msk) << 2;   // halfword off, b64 write
  const int bg  = blockIdx.x * 32;

  __shared__ __align__(16) unsigned short Hh[2][32][64];  // f16 bits
  __shared__ __align__(16) float Xs[32][42];   // stride 42: 2-way max (free)

  // ---- stage x: x[bg+mm][st][c] -> Xs[mm][2*st+c] ----
  {
    const size_t xoff = (size_t)blockIdx.x * 1280;
    for (int i = tid; i < 1280; i += 256) {
      int mm = i / 40, r = i - mm * 40;
      float v = (xoff + i < (size_t)B * 40) ? x[xoff + i] : 0.0f;
      Xs[mm][r] = v;
    }
  }

  // ---- encoder weights: A frags (single f16 RNE, f-pack, SCALED) ----
  half8v eA[4][2];
  float4v ebs[4], eWa[4], eWb[4];
#pragma unroll
  for (int gi = 0; gi < 4; ++gi) {
    const float gsc = (gi == 2) ? TWO_LOG2E : -LOG2E;
    const int nA = m + 16 * (4 * gi + w);
#pragma unroll
    for (int q = 0; q < 2; ++q) {
      const float* wp = &eWhh[nA * 64 + 32 * q + 8 * tg];
      float4v w0 = *(const float4v*)wp;
      float4v w1 = *(const float4v*)(wp + 4);
      half8v hi;
#pragma unroll
      for (int e = 0; e < 4; ++e) {
        hi[e]     = (_Float16)(w0[e] * gsc);
        hi[4 + e] = (_Float16)(w1[e] * gsc);
      }
      eA[gi][q] = hi;
    }
#pragma unroll
    for (int r = 0; r < 4; ++r) {
      const int n = 64 * gi + 16 * w + 4 * tg + r;
      ebs[gi][r] = (ebih[n] + ebhh[n]) * gsc;
      eWa[gi][r] = eWih[n * 2 + 0] * gsc;
      eWb[gi][r] = eWih[n * 2 + 1] * gsc;
    }
  }

  __syncthreads();   // Xs ready

  float4v c0 = {0.f, 0.f, 0.f, 0.f}, c1 = {0.f, 0.f, 0.f, 0.f};
  const half8v z8 = {0, 0, 0, 0, 0, 0, 0, 0};
  half8v b0[2] = {z8, z8}, b1[2] = {z8, z8};
  int p = 0;

  // ---- encoder: 20 steps ----
#pragma unroll 2
  for (int st = 0; st < 20; ++st) {
    const float xa0 = Xs[m][2 * st], xb0 = Xs[m][2 * st + 1];
    const float xa1 = Xs[m + 16][2 * st], xb1 = Xs[m + 16][2 * st + 1];
    float4v a0[4], a1[4];
#pragma unroll
    for (int gi = 0; gi < 4; ++gi) {
      float4v i0 = eWa[gi] * xa0 + (eWb[gi] * xb0 + ebs[gi]);   // pk_fma x4
      float4v i1 = eWa[gi] * xa1 + (eWb[gi] * xb1 + ebs[gi]);
      float4v a = MFMAH(eA[gi][0], b0[0], i0);
      a = MFMAH(eA[gi][1], b0[1], a);
      a0[gi] = a;
      float4v b = MFMAH(eA[gi][0], b1[0], i1);
      b = MFMAH(eA[gi][1], b1[1], b);
      a1[gi] = b;
    }
    short4v hh0, hh1;
    cellact(a0, c0, hh0);
    cellact(a1, c1, hh1);
    *(short4v*)&Hh[p][m][wslot]      = hh0;
    *(short4v*)&Hh[p][m + 16][wslot] = hh1;
    __syncthreads();
#pragma unroll
    for (int q = 0; q < 2; ++q) {
      const int rs = (((8 * q) | (2 * tg)) ^ msk) << 2;
      b0[q] = *(const half8v*)&Hh[p][m][rs];
      b1[q] = *(const half8v*)&Hh[p][m + 16][rs];
    }
    p ^= 1;
  }

  // ---- decoder weights: Wsum = dWih + dWhh (input == hidden), SCALED ----
  half8v dA[4][2];
  float4v dbsv[4];
#pragma unroll
  for (int gi = 0; gi < 4; ++gi) {
    const float gsc = (gi == 2) ? TWO_LOG2E : -LOG2E;
    const int nA = m + 16 * (4 * gi + w);
#pragma unroll
    for (int q = 0; q < 2; ++q) {
      const float* wpa = &dWih[nA * 64 + 32 * q + 8 * tg];
      const float* wpb = &dWhh[nA * 64 + 32 * q + 8 * tg];
      float4v a0v = *(const float4v*)wpa;
      float4v a1v = *(const float4v*)(wpa + 4);
      float4v b0v = *(const float4v*)wpb;
      float4v b1v = *(const float4v*)(wpb + 4);
      half8v hi;
#pragma unroll
      for (int e = 0; e < 4; ++e) {
        hi[e]     = (_Float16)((a0v[e] + b0v[e]) * gsc);
        hi[4 + e] = (_Float16)((a1v[e] + b1v[e]) * gsc);
      }
      dA[gi][q] = hi;
    }
#pragma unroll
    for (int r = 0; r < 4; ++r) {
      const int n = 64 * gi + 16 * w + 4 * tg + r;
      dbsv[gi][r] = (dbih[n] + dbhh[n]) * gsc;
    }
  }

  // ---- linear-layer A-frag (rows 0,1; single f16 RNE; same f-pack) ----
  half8v LA[2];
#pragma unroll
  for (int q = 0; q < 2; ++q) {
    half8v hi;
#pragma unroll
    for (int e = 0; e < 4; ++e) {
      const int k0 = 32 * q + 8 * tg + e;
      float v0 = (m < 2) ? linW[m * 64 + k0] : 0.0f;
      float v1 = (m < 2) ? linW[m * 64 + k0 + 4] : 0.0f;
      hi[e] = (_Float16)v0;
      hi[4 + e] = (_Float16)v1;
    }
    LA[q] = hi;
  }
  float4v lbinit = {0.f, 0.f, 0.f, 0.f};
  if (tg == 0) { lbinit[0] = linb[0]; lbinit[1] = linb[1]; }

  // ---- decoder: 30 steps; out[st] emitted via MFMA after the exchange ----
#pragma unroll 2
  for (int st = 0; st < 30; ++st) {
    float4v a0[4], a1[4];
#pragma unroll
    for (int gi = 0; gi < 4; ++gi) {
      float4v a = MFMAH(dA[gi][0], b0[0], dbsv[gi]);
      a = MFMAH(dA[gi][1], b0[1], a);
      a0[gi] = a;
      float4v b = MFMAH(dA[gi][0], b1[0], dbsv[gi]);
      b = MFMAH(dA[gi][1], b1[1], b);
      a1[gi] = b;
    }
    short4v hh0, hh1;
    cellact(a0, c0, hh0);
    cellact(a1, c1, hh1);
    *(short4v*)&Hh[p][m][wslot]      = hh0;
    *(short4v*)&Hh[p][m + 16][wslot] = hh1;
    __syncthreads();
#pragma unroll
    for (int q = 0; q < 2; ++q) {
      const int rs = (((8 * q) | (2 * tg)) ^ msk) << 2;
      b0[q] = *(const half8v*)&Hh[p][m][rs];
      b1[q] = *(const half8v*)&Hh[p][m + 16][rs];
    }
    // b-frags now hold h_st -> emit out[st] on the matrix pipe.
    if (w == 0) {
      float4v la = lbinit;
      la = MFMAH(LA[0], b0[0], la);
      la = MFMAH(LA[1], b0[1], la);
      if (l < 16 && (bg + l) < B) {
        size_t oidx = ((size_t)(bg + l) * 30 + st) * 2;
        *(float2*)&out[oidx] = make_float2(la[0], la[1]);
      }
    } else if (w == 1) {
      float4v la = lbinit;
      la = MFMAH(LA[0], b1[0], la);
      la = MFMAH(LA[1], b1[1], la);
      if (l < 16 && (bg + 16 + l) < B) {
        size_t oidx = ((size_t)(bg + 16 + l) * 30 + st) * 2;
        *(float2*)&out[oidx] = make_float2(la[0], la[1]);
      }
    }
    p ^= 1;
  }
}

extern "C" void kernel_launch(void* const* d_in, const int* in_sizes, int n_in,
                              void* d_out, int out_size, void* d_ws, size_t ws_size,
                              hipStream_t stream) {
  (void)n_in; (void)out_size; (void)d_ws; (void)ws_size;
  const float* x    = (const float*)d_in[0];
  const float* eWih = (const float*)d_in[1];
  const float* eWhh = (const float*)d_in[2];
  const float* ebih = (const float*)d_in[3];
  const float* ebhh = (const float*)d_in[4];
  const float* dWih = (const float*)d_in[5];
  const float* dWhh = (const float*)d_in[6];
  const float* dbih = (const float*)d_in[7];
  const float* dbhh = (const float*)d_in[8];
  const float* linW = (const float*)d_in[9];
  const float* linb = (const float*)d_in[10];

  const int B = in_sizes[0] / 40;          // [B][20][2]
  const int grid = (B + 31) / 32;          // 32 batch elems per block (2 tiles)
  lstm_fused<<<grid, 256, 0, stream>>>(x, eWih, eWhh, ebih, ebhh,
                                       dWih, dWhh, dbih, dbhh, linW, linb,
                                       (float*)d_out, B);
}

// Round 6
// 437.578 us; speedup vs baseline: 1.4168x; 1.4168x over previous
//
#include <hip/hip_runtime.h>

// LSTM enc(20, in=2) + dec(30, in=h) fused, HID=64, f32 I/O.
// Gates-transposed MFMA recurrence, v_mfma_f32_16x16x32_f16 (K=32).
//   D[n][m] = sum_k W[n][k] h[m][k]; C/D: col=l&15, row=4*(l>>4)+r (m89,
//   dtype-independent).
// k-relabeling: BOTH operands packed with f(q,tg,e) = 32q + 8tg + e
// (a bijection over [0,64); any f applied to A and B identically leaves
// D unchanged). So A-frag q = 8 CONTIGUOUS floats W[n][32q+8tg .. +7],
// and B-frag q = h[32q+8tg .. +7] = one b128 from identity-layout LDS.
// Wave w owns hidden j in [16w,16w+16). Cross-wave h exchange through a
// double-buffered XOR-swizzled LDS tile, 1 barrier/step:
//   write: wave w lane(m,tg) stores jb=4w+tg at slot jb^(m&14) (free)
//   read:  b128 at slot (8q+2tg)^(m&14) -> h[32q+8tg..+7] (free)
// Output path: Linear(h) via deferred MFMA (wave0=tile0, wave1=tile1) on the
// b-frags read at iteration end; LA-frag same f-pack (single f16, NOT scaled).
// TWO batch tiles per block (32 batch) share weight VGPRs and the barrier.
//
// R6: scale-folded gates (exp2 domain) + single-rcp fused cell math:
//   7 trans/h (5 exp2 + 2 rcp).  886->830 rocprof; VALU 64->59.
// R7: pk-f32 vectorized cell math + unroll 2.  VALU 59->55.7.
// R8: bf16 -> f16 (f16-RNE h, no h-lo): 48 -> 32 MFMAs/step.  rocprof
//   850->655, wall 709->570; absmax UNCHANGED 2.4e-4.
// R9: single f16-RNE W (drop W-lo): 32 -> 16 MFMAs/step.  rocprof 655->548,
//   wall 570->468, MfmaUtil 18.1 (predicted 18), absmax STILL 2.4e-4.
// R10 FAILED: __launch_bounds__(256,4) made the allocator clamp arch VGPRs
//   to 64 -> scratch spills (FETCH 11MB->584MB, WRITE 30->907MB), wall
//   468->620 despite occupancy 22.5->43.6%.  Lesson: residency IS the
//   limiter (occupancy did rise and absorbed idle), but the live-state
//   total sits between the 4-wave (128) and 2-wave (256) budgets.
// R11 (this round): probe the intermediate -- __launch_bounds__(256,3),
//   budget ~170 regs/wave.  Demand (~108 reported + acc overhead) should
//   fit with ~zero spill; residency 2 -> 3 blocks/CU absorbs the 20% idle
//   measured at R9.  Pass/fail: FETCH_SIZE back at ~11k KB.  If it spills
//   again, next round moves W A-frags to a swizzled LDS tile (-64 regs).

#define LOG2E 1.44269504088896340736f
#define TWO_LOG2E 2.88539008177792681472f

typedef __attribute__((ext_vector_type(4))) short short4v;
typedef __attribute__((ext_vector_type(4))) float float4v;
typedef _Float16 __attribute__((ext_vector_type(8))) half8v;

#if defined(__HIP_DEVICE_COMPILE__)
#define MFMAH(a, b, c) __builtin_amdgcn_mfma_f32_16x16x32_f16((a), (b), (c), 0, 0, 0)
#else
#define MFMAH(a, b, c) (c)
#endif

__device__ __forceinline__ float4v exp2v4(float4v x) {
  float4v r;
  r[0] = __builtin_amdgcn_exp2f(x[0]);
  r[1] = __builtin_amdgcn_exp2f(x[1]);
  r[2] = __builtin_amdgcn_exp2f(x[2]);
  r[3] = __builtin_amdgcn_exp2f(x[3]);
  return r;
}
__device__ __forceinline__ float4v rcpv4(float4v x) {
  float4v r;
  r[0] = __builtin_amdgcn_rcpf(x[0]);
  r[1] = __builtin_amdgcn_rcpf(x[1]);
  r[2] = __builtin_amdgcn_rcpf(x[2]);
  r[3] = __builtin_amdgcn_rcpf(x[3]);
  return r;
}

// Fused LSTM cell update on 4 rows (pk-f32).  a[0..3] = gates i,f,g,o
// PRE-SCALED (i,f,o by -log2e; g by 2log2e).  c holds 2log2e*cell.
// Emits h as 4 f16 (RNE) bit-patterns.
__device__ __forceinline__ void cellact(const float4v* a, float4v& c,
                                        short4v& hh) {
  const float4v one = {1.f, 1.f, 1.f, 1.f};
  const float4v clo = {-36.f, -36.f, -36.f, -36.f};
  const float4v chi = {36.f, 36.f, 36.f, 36.f};
  float4v Ei = exp2v4(a[0]);                    // e^{-i}
  float4v Ef = exp2v4(a[1]);                    // e^{-f}
  float4v Eg = exp2v4(a[2]);                    // e^{2g}
  float4v Eo = exp2v4(a[3]);                    // e^{-o}
  float4v t1 = one + Ei;
  float4v t2 = one + Eg;
  float4v t3 = one + Ef;
  float4v t4s = Eg * TWO_LOG2E - TWO_LOG2E;     // 2log2e*(Eg-1), pk_fma
  float4v P = t1 * t2;
  float4v num = c * P + t4s * t3;               // pk_mul + pk_fma
  float4v cs = num * rcpv4(P * t3);             // 2log2e * c_new
  c = cs;
  float4v cl = __builtin_elementwise_min(__builtin_elementwise_max(cs, clo), chi);
  float4v Ec = exp2v4(cl);                      // e^{2*c_new}
  float4v h = (Ec - one) * rcpv4((one + Ec) * (one + Eo));
#pragma unroll
  for (int r = 0; r < 4; ++r) {
    _Float16 hf = (_Float16)h[r];               // v_cvt_f16_f32 (RNE)
    hh[r] = (short)__builtin_bit_cast(unsigned short, hf);
  }
}

__global__ __launch_bounds__(256, 3) void lstm_fused(
    const float* __restrict__ x,     // [B][20][2]
    const float* __restrict__ eWih,  // [256][2]
    const float* __restrict__ eWhh,  // [256][64]
    const float* __restrict__ ebih,  // [256]
    const float* __restrict__ ebhh,  // [256]
    const float* __restrict__ dWih,  // [256][64]
    const float* __restrict__ dWhh,  // [256][64]
    const float* __restrict__ dbih,  // [256]
    const float* __restrict__ dbhh,  // [256]
    const float* __restrict__ linW,  // [2][64]
    const float* __restrict__ linb,  // [2]
    float* __restrict__ out,         // [B][30][2]
    int B) {
  const int tid = threadIdx.x;
  const int w   = tid >> 6;    // wave: hidden block [16w, 16w+16)
  const int l   = tid & 63;
  const int m   = l & 15;      // batch col within tile
  const int tg  = l >> 4;
  const int msk = m & 14;
  const int wslot = (((w << 2) | tg) ^ msk) << 2;   // halfword off, b64 write
  const int bg  = blockIdx.x * 32;

  __shared__ __align__(16) unsigned short Hh[2][32][64];  // f16 bits
  __shared__ __align__(16) float Xs[32][42];   // stride 42: 2-way max (free)

  // ---- stage x: x[bg+mm][st][c] -> Xs[mm][2*st+c] ----
  {
    const size_t xoff = (size_t)blockIdx.x * 1280;
    for (int i = tid; i < 1280; i += 256) {
      int mm = i / 40, r = i - mm * 40;
      float v = (xoff + i < (size_t)B * 40) ? x[xoff + i] : 0.0f;
      Xs[mm][r] = v;
    }
  }

  // ---- encoder weights: A frags (single f16 RNE, f-pack, SCALED) ----
  half8v eA[4][2];
  float4v ebs[4], eWa[4], eWb[4];
#pragma unroll
  for (int gi = 0; gi < 4; ++gi) {
    const float gsc = (gi == 2) ? TWO_LOG2E : -LOG2E;
    const int nA = m + 16 * (4 * gi + w);
#pragma unroll
    for (int q = 0; q < 2; ++q) {
      const float* wp = &eWhh[nA * 64 + 32 * q + 8 * tg];
      float4v w0 = *(const float4v*)wp;
      float4v w1 = *(const float4v*)(wp + 4);
      half8v hi;
#pragma unroll
      for (int e = 0; e < 4; ++e) {
        hi[e]     = (_Float16)(w0[e] * gsc);
        hi[4 + e] = (_Float16)(w1[e] * gsc);
      }
      eA[gi][q] = hi;
    }
#pragma unroll
    for (int r = 0; r < 4; ++r) {
      const int n = 64 * gi + 16 * w + 4 * tg + r;
      ebs[gi][r] = (ebih[n] + ebhh[n]) * gsc;
      eWa[gi][r] = eWih[n * 2 + 0] * gsc;
      eWb[gi][r] = eWih[n * 2 + 1] * gsc;
    }
  }

  __syncthreads();   // Xs ready

  float4v c0 = {0.f, 0.f, 0.f, 0.f}, c1 = {0.f, 0.f, 0.f, 0.f};
  const half8v z8 = {0, 0, 0, 0, 0, 0, 0, 0};
  half8v b0[2] = {z8, z8}, b1[2] = {z8, z8};
  int p = 0;

  // ---- encoder: 20 steps ----
#pragma unroll 2
  for (int st = 0; st < 20; ++st) {
    const float xa0 = Xs[m][2 * st], xb0 = Xs[m][2 * st + 1];
    const float xa1 = Xs[m + 16][2 * st], xb1 = Xs[m + 16][2 * st + 1];
    float4v a0[4], a1[4];
#pragma unroll
    for (int gi = 0; gi < 4; ++gi) {
      float4v i0 = eWa[gi] * xa0 + (eWb[gi] * xb0 + ebs[gi]);   // pk_fma x4
      float4v i1 = eWa[gi] * xa1 + (eWb[gi] * xb1 + ebs[gi]);
      float4v a = MFMAH(eA[gi][0], b0[0], i0);
      a = MFMAH(eA[gi][1], b0[1], a);
      a0[gi] = a;
      float4v b = MFMAH(eA[gi][0], b1[0], i1);
      b = MFMAH(eA[gi][1], b1[1], b);
      a1[gi] = b;
    }
    short4v hh0, hh1;
    cellact(a0, c0, hh0);
    cellact(a1, c1, hh1);
    *(short4v*)&Hh[p][m][wslot]      = hh0;
    *(short4v*)&Hh[p][m + 16][wslot] = hh1;
    __syncthreads();
#pragma unroll
    for (int q = 0; q < 2; ++q) {
      const int rs = (((8 * q) | (2 * tg)) ^ msk) << 2;
      b0[q] = *(const half8v*)&Hh[p][m][rs];
      b1[q] = *(const half8v*)&Hh[p][m + 16][rs];
    }
    p ^= 1;
  }

  // ---- decoder weights: Wsum = dWih + dWhh (input == hidden), SCALED ----
  half8v dA[4][2];
  float4v dbsv[4];
#pragma unroll
  for (int gi = 0; gi < 4; ++gi) {
    const float gsc = (gi == 2) ? TWO_LOG2E : -LOG2E;
    const int nA = m + 16 * (4 * gi + w);
#pragma unroll
    for (int q = 0; q < 2; ++q) {
      const float* wpa = &dWih[nA * 64 + 32 * q + 8 * tg];
      const float* wpb = &dWhh[nA * 64 + 32 * q + 8 * tg];
      float4v a0v = *(const float4v*)wpa;
      float4v a1v = *(const float4v*)(wpa + 4);
      float4v b0v = *(const float4v*)wpb;
      float4v b1v = *(const float4v*)(wpb + 4);
      half8v hi;
#pragma unroll
      for (int e = 0; e < 4; ++e) {
        hi[e]     = (_Float16)((a0v[e] + b0v[e]) * gsc);
        hi[4 + e] = (_Float16)((a1v[e] + b1v[e]) * gsc);
      }
      dA[gi][q] = hi;
    }
#pragma unroll
    for (int r = 0; r < 4; ++r) {
      const int n = 64 * gi + 16 * w + 4 * tg + r;
      dbsv[gi][r] = (dbih[n] + dbhh[n]) * gsc;
    }
  }

  // ---- linear-layer A-frag (rows 0,1; single f16 RNE; same f-pack) ----
  half8v LA[2];
#pragma unroll
  for (int q = 0; q < 2; ++q) {
    half8v hi;
#pragma unroll
    for (int e = 0; e < 4; ++e) {
      const int k0 = 32 * q + 8 * tg + e;
      float v0 = (m < 2) ? linW[m * 64 + k0] : 0.0f;
      float v1 = (m < 2) ? linW[m * 64 + k0 + 4] : 0.0f;
      hi[e] = (_Float16)v0;
      hi[4 + e] = (_Float16)v1;
    }
    LA[q] = hi;
  }
  float4v lbinit = {0.f, 0.f, 0.f, 0.f};
  if (tg == 0) { lbinit[0] = linb[0]; lbinit[1] = linb[1]; }

  // ---- decoder: 30 steps; out[st] emitted via MFMA after the exchange ----
#pragma unroll 2
  for (int st = 0; st < 30; ++st) {
    float4v a0[4], a1[4];
#pragma unroll
    for (int gi = 0; gi < 4; ++gi) {
      float4v a = MFMAH(dA[gi][0], b0[0], dbsv[gi]);
      a = MFMAH(dA[gi][1], b0[1], a);
      a0[gi] = a;
      float4v b = MFMAH(dA[gi][0], b1[0], dbsv[gi]);
      b = MFMAH(dA[gi][1], b1[1], b);
      a1[gi] = b;
    }
    short4v hh0, hh1;
    cellact(a0, c0, hh0);
    cellact(a1, c1, hh1);
    *(short4v*)&Hh[p][m][wslot]      = hh0;
    *(short4v*)&Hh[p][m + 16][wslot] = hh1;
    __syncthreads();
#pragma unroll
    for (int q = 0; q < 2; ++q) {
      const int rs = (((8 * q) | (2 * tg)) ^ msk) << 2;
      b0[q] = *(const half8v*)&Hh[p][m][rs];
      b1[q] = *(const half8v*)&Hh[p][m + 16][rs];
    }
    // b-frags now hold h_st -> emit out[st] on the matrix pipe.
    if (w == 0) {
      float4v la = lbinit;
      la = MFMAH(LA[0], b0[0], la);
      la = MFMAH(LA[1], b0[1], la);
      if (l < 16 && (bg + l) < B) {
        size_t oidx = ((size_t)(bg + l) * 30 + st) * 2;
        *(float2*)&out[oidx] = make_float2(la[0], la[1]);
      }
    } else if (w == 1) {
      float4v la = lbinit;
      la = MFMAH(LA[0], b1[0], la);
      la = MFMAH(LA[1], b1[1], la);
      if (l < 16 && (bg + 16 + l) < B) {
        size_t oidx = ((size_t)(bg + 16 + l) * 30 + st) * 2;
        *(float2*)&out[oidx] = make_float2(la[0], la[1]);
      }
    }
    p ^= 1;
  }
}

extern "C" void kernel_launch(void* const* d_in, const int* in_sizes, int n_in,
                              void* d_out, int out_size, void* d_ws, size_t ws_size,
                              hipStream_t stream) {
  (void)n_in; (void)out_size; (void)d_ws; (void)ws_size;
  const float* x    = (const float*)d_in[0];
  const float* eWih = (const float*)d_in[1];
  const float* eWhh = (const float*)d_in[2];
  const float* ebih = (const float*)d_in[3];
  const float* ebhh = (const float*)d_in[4];
  const float* dWih = (const float*)d_in[5];
  const float* dWhh = (const float*)d_in[6];
  const float* dbih = (const float*)d_in[7];
  const float* dbhh = (const float*)d_in[8];
  const float* linW = (const float*)d_in[9];
  const float* linb = (const float*)d_in[10];

  const int B = in_sizes[0] / 40;          // [B][20][2]
  const int grid = (B + 31) / 32;          // 32 batch elems per block (2 tiles)
  lstm_fused<<<grid, 256, 0, stream>>>(x, eWih, eWhh, ebih, ebhh,
                                       dWih, dWhh, dbih, dbhh, linW, linb,
                                       (float*)d_out, B);
}